// Round 1
// baseline (1462.953 us; speedup 1.0000x reference)
//
#include <hip/hip_runtime.h>
#include <hip/hip_bf16.h>
#include <math.h>

#define DMODEL 256
#define NH 8
#define DKH 32
#define SEQ 197
#define BATCH 64
#define NPAT 196
#define FFDIM 1024
#define KCONV 768
#define EPSLN 1e-5f

// ---------------------------------------------------------------------------
// Patch-embed conv as GEMM: M=B*196=12544, K=3*16*16=768, N=256.
// A is im2col'd on the fly; epilogue adds conv_b + pos and writes into e
// at rows (b*197 + s), leaving row 196 (cls) for cls_kernel.
// ---------------------------------------------------------------------------
__global__ __launch_bounds__(256) void conv_gemm_kernel(
    const float* __restrict__ img, const float* __restrict__ W,
    const float* __restrict__ cb, const float* __restrict__ pos,
    float* __restrict__ e)
{
  __shared__ float As[16][65];
  __shared__ float Bs[16][65];
  int m0 = blockIdx.x * 64, n0 = blockIdx.y * 64;
  int t = threadIdx.x;
  int ar = t >> 2;
  int ac = (t & 3) << 2;
  int ty = t >> 4, tx = t & 15;
  int m = m0 + ar;
  int b = m / NPAT, p = m - b * NPAT;
  int py = p / 14, px = p - py * 14;
  const float* abase = img + ((size_t)b * 3) * (224 * 224) + (py * 16) * 224 + px * 16;
  const float* wbase = W + (size_t)(n0 + ar) * KCONV + ac;
  float acc[4][4] = {};
  for (int k0 = 0; k0 < KCONV; k0 += 16) {
    int c  = k0 >> 8;           // channel
    int rr = (k0 & 255) >> 4;   // row within patch
    float4 av = *(const float4*)(abase + (size_t)c * (224 * 224) + rr * 224 + ac);
    float4 wv = *(const float4*)(wbase + k0);
    As[ac + 0][ar] = av.x; As[ac + 1][ar] = av.y;
    As[ac + 2][ar] = av.z; As[ac + 3][ar] = av.w;
    Bs[ac + 0][ar] = wv.x; Bs[ac + 1][ar] = wv.y;
    Bs[ac + 2][ar] = wv.z; Bs[ac + 3][ar] = wv.w;
    __syncthreads();
#pragma unroll
    for (int kk = 0; kk < 16; kk++) {
      float a[4], bb[4];
#pragma unroll
      for (int i = 0; i < 4; i++) a[i] = As[kk][ty * 4 + i];
#pragma unroll
      for (int j = 0; j < 4; j++) bb[j] = Bs[kk][tx * 4 + j];
#pragma unroll
      for (int i = 0; i < 4; i++)
#pragma unroll
        for (int j = 0; j < 4; j++) acc[i][j] += a[i] * bb[j];
    }
    __syncthreads();
  }
#pragma unroll
  for (int i = 0; i < 4; i++) {
    int mm = m0 + ty * 4 + i;
    int bb2 = mm / NPAT, s = mm - bb2 * NPAT;
#pragma unroll
    for (int j = 0; j < 4; j++) {
      int n = n0 + tx * 4 + j;
      e[((size_t)bb2 * SEQ + s) * DMODEL + n] = acc[i][j] + cb[n] + pos[s * DMODEL + n];
    }
  }
}

// cls row (index 196, appended at END per reference) + pos
__global__ void cls_kernel(const float* __restrict__ cls, const float* __restrict__ pos,
                           float* __restrict__ e)
{
  int b = blockIdx.x, d = threadIdx.x;
  e[((size_t)b * SEQ + NPAT) * DMODEL + d] = cls[d] + pos[NPAT * DMODEL + d];
}

// ---------------------------------------------------------------------------
// Generic C = A @ W^T (+bias)(+residual)(+relu).  W is (N,K) row-major.
// M,N divisible by 64, K divisible by 16 for all call sites.
// ---------------------------------------------------------------------------
__global__ __launch_bounds__(256) void gemm_xwt_kernel(
    const float* __restrict__ A, const float* __restrict__ W,
    const float* __restrict__ bias, const float* __restrict__ res,
    float* __restrict__ out, int M, int N, int K, int relu)
{
  __shared__ float As[16][65];
  __shared__ float Bs[16][65];
  int m0 = blockIdx.x * 64, n0 = blockIdx.y * 64;
  int t = threadIdx.x;
  int ar = t >> 2;
  int ac = (t & 3) << 2;
  int ty = t >> 4, tx = t & 15;
  const float* abase = A + (size_t)(m0 + ar) * K + ac;
  const float* wbase = W + (size_t)(n0 + ar) * K + ac;
  float acc[4][4] = {};
  for (int k0 = 0; k0 < K; k0 += 16) {
    float4 av = *(const float4*)(abase + k0);
    float4 wv = *(const float4*)(wbase + k0);
    As[ac + 0][ar] = av.x; As[ac + 1][ar] = av.y;
    As[ac + 2][ar] = av.z; As[ac + 3][ar] = av.w;
    Bs[ac + 0][ar] = wv.x; Bs[ac + 1][ar] = wv.y;
    Bs[ac + 2][ar] = wv.z; Bs[ac + 3][ar] = wv.w;
    __syncthreads();
#pragma unroll
    for (int kk = 0; kk < 16; kk++) {
      float a[4], bb[4];
#pragma unroll
      for (int i = 0; i < 4; i++) a[i] = As[kk][ty * 4 + i];
#pragma unroll
      for (int j = 0; j < 4; j++) bb[j] = Bs[kk][tx * 4 + j];
#pragma unroll
      for (int i = 0; i < 4; i++)
#pragma unroll
        for (int j = 0; j < 4; j++) acc[i][j] += a[i] * bb[j];
    }
    __syncthreads();
  }
#pragma unroll
  for (int i = 0; i < 4; i++) {
    int mm = m0 + ty * 4 + i;
#pragma unroll
    for (int j = 0; j < 4; j++) {
      int n = n0 + tx * 4 + j;
      float vv = acc[i][j];
      if (bias) vv += bias[n];
      if (res) vv += res[(size_t)mm * N + n];
      if (relu) vv = fmaxf(vv, 0.0f);
      out[(size_t)mm * N + n] = vv;
    }
  }
}

// ---------------------------------------------------------------------------
// Fused attention for one (b,h): softmax(q k^T / sqrt(dk)) v
// q,k,v,o all in (B,S,D) layout with head h occupying cols h*32..h*32+31.
// k,v staged in LDS; queries processed in chunks of 8 (LDS < 64 KB).
// ---------------------------------------------------------------------------
__global__ __launch_bounds__(256) void attn_kernel(
    const float* __restrict__ q, const float* __restrict__ k,
    const float* __restrict__ v, const int* __restrict__ mask,
    float* __restrict__ o)
{
  __shared__ float ks[SEQ][DKH + 1];
  __shared__ float vs[SEQ][DKH + 1];
  __shared__ float qs[8][DKH + 1];
  __shared__ float ss[8][SEQ + 1];
  int bh = blockIdx.x;
  int b = bh / NH, h = bh - b * NH;
  int t = threadIdx.x;
  const float* kb = k + (size_t)b * SEQ * DMODEL + h * DKH;
  const float* vb = v + (size_t)b * SEQ * DMODEL + h * DKH;
  const float* qb = q + (size_t)b * SEQ * DMODEL + h * DKH;
  for (int idx = t; idx < SEQ * DKH; idx += 256) {
    int s = idx / DKH, d = idx - s * DKH;
    ks[s][d] = kb[(size_t)s * DMODEL + d];
    vs[s][d] = vb[(size_t)s * DMODEL + d];
  }
  __syncthreads();
  const float scale = 0.17677669529663687f;  // 1/sqrt(32)
  for (int q0 = 0; q0 < SEQ; q0 += 8) {
    int nq = min(8, SEQ - q0);
    if (t < nq * DKH) {
      int qi = t >> 5, d = t & 31;
      qs[qi][d] = qb[(size_t)(q0 + qi) * DMODEL + d];
    }
    __syncthreads();
    for (int idx = t; idx < nq * SEQ; idx += 256) {
      int qi = idx / SEQ, kj = idx - qi * SEQ;
      float acc = 0.0f;
#pragma unroll
      for (int d = 0; d < DKH; d++) acc += qs[qi][d] * ks[kj][d];
      acc *= scale;
      if (mask && mask[(q0 + qi) * SEQ + kj] == 0) acc = -INFINITY;
      ss[qi][kj] = acc;
    }
    __syncthreads();
    // parallel softmax: 8 groups of 32 lanes, one row each
    {
      int grp = t >> 5, lane = t & 31;
      if (grp < nq) {
        float mx = -INFINITY;
        for (int j = lane; j < SEQ; j += 32) mx = fmaxf(mx, ss[grp][j]);
        for (int off = 16; off; off >>= 1) mx = fmaxf(mx, __shfl_down(mx, off, 32));
        mx = __shfl(mx, 0, 32);
        float sum = 0.0f;
        for (int j = lane; j < SEQ; j += 32) {
          float ex = __expf(ss[grp][j] - mx);
          ss[grp][j] = ex;
          sum += ex;
        }
        for (int off = 16; off; off >>= 1) sum += __shfl_down(sum, off, 32);
        sum = __shfl(sum, 0, 32);
        float inv = 1.0f / sum;
        for (int j = lane; j < SEQ; j += 32) ss[grp][j] *= inv;
      }
    }
    __syncthreads();
    if (t < nq * DKH) {
      int qi = t >> 5, d = t & 31;
      float acc = 0.0f;
      for (int kj = 0; kj < SEQ; kj++) acc += ss[qi][kj] * vs[kj][d];
      o[((size_t)b * SEQ + q0 + qi) * DMODEL + h * DKH + d] = acc;
    }
    __syncthreads();
  }
}

// ---------------------------------------------------------------------------
// LayerNorm over D=256, one 64-lane wave per row (4 rows per block).
// ---------------------------------------------------------------------------
__global__ __launch_bounds__(256) void ln_kernel(
    const float* __restrict__ x, const float* __restrict__ g,
    const float* __restrict__ bt, float* __restrict__ out)
{
  int wave = threadIdx.x >> 6, lane = threadIdx.x & 63;
  int row = blockIdx.x * 4 + wave;
  const float* xr = x + (size_t)row * DMODEL;
  float v0 = xr[lane], v1 = xr[lane + 64], v2 = xr[lane + 128], v3 = xr[lane + 192];
  float s = v0 + v1 + v2 + v3;
  for (int off = 32; off; off >>= 1) s += __shfl_down(s, off);
  s = __shfl(s, 0);
  float mean = s * (1.0f / DMODEL);
  float d0 = v0 - mean, d1 = v1 - mean, d2 = v2 - mean, d3 = v3 - mean;
  float vv = d0 * d0 + d1 * d1 + d2 * d2 + d3 * d3;
  for (int off = 32; off; off >>= 1) vv += __shfl_down(vv, off);
  vv = __shfl(vv, 0);
  float inv = rsqrtf(vv * (1.0f / DMODEL) + EPSLN);
  float* orow = out + (size_t)row * DMODEL;
  orow[lane]       = d0 * inv * g[lane]       + bt[lane];
  orow[lane + 64]  = d1 * inv * g[lane + 64]  + bt[lane + 64];
  orow[lane + 128] = d2 * inv * g[lane + 128] + bt[lane + 128];
  orow[lane + 192] = d3 * inv * g[lane + 192] + bt[lane + 192];
}

// ---------------------------------------------------------------------------
extern "C" void kernel_launch(void* const* d_in, const int* in_sizes, int n_in,
                              void* d_out, int out_size, void* d_ws, size_t ws_size,
                              hipStream_t stream)
{
  const float* enc    = (const float*)d_in[0];
  const float* dec_in = (const float*)d_in[1];
  const int*   mask   = (const int*)  d_in[2];
  const float* conv_w = (const float*)d_in[3];
  const float* conv_b = (const float*)d_in[4];
  const float* cls    = (const float*)d_in[5];
  const float* pos    = (const float*)d_in[6];
  const float* ff_w1  = (const float*)d_in[7];
  const float* ff_b1  = (const float*)d_in[8];
  const float* ff_w2  = (const float*)d_in[9];
  const float* ff_b2  = (const float*)d_in[10];
  const float* ln1_g  = (const float*)d_in[11];
  const float* ln1_b  = (const float*)d_in[12];
  const float* ln2_g  = (const float*)d_in[13];
  const float* ln2_b  = (const float*)d_in[14];
  const float* ln3_g  = (const float*)d_in[15];
  const float* ln3_b  = (const float*)d_in[16];
  const float* a1_wq = (const float*)d_in[17]; const float* a1_bq = (const float*)d_in[18];
  const float* a1_wk = (const float*)d_in[19]; const float* a1_bk = (const float*)d_in[20];
  const float* a1_wv = (const float*)d_in[21]; const float* a1_bv = (const float*)d_in[22];
  const float* a1_wo = (const float*)d_in[23]; const float* a1_bo = (const float*)d_in[24];
  const float* a2_wq = (const float*)d_in[25]; const float* a2_bq = (const float*)d_in[26];
  const float* a2_wk = (const float*)d_in[27]; const float* a2_bk = (const float*)d_in[28];
  const float* a2_wv = (const float*)d_in[29]; const float* a2_bv = (const float*)d_in[30];
  const float* a2_wo = (const float*)d_in[31]; const float* a2_bo = (const float*)d_in[32];

  const size_t SLOT = (size_t)BATCH * SEQ * DMODEL;  // 3,227,648 elems
  float* ws = (float*)d_ws;
  float* e_buf = ws + 0 * SLOT;
  float* q_buf = ws + 1 * SLOT;
  float* k_buf = ws + 2 * SLOT;
  float* v_buf = ws + 3 * SLOT;
  float* o_buf = ws + 4 * SLOT;
  float* t_buf = ws + 5 * SLOT;
  float* x1    = ws + 6 * SLOT;
  float* x2    = ws + 7 * SLOT;
  float* h_buf = ws + 0 * SLOT;  // aliases e/q/k/v (dead by FF time): 4*SLOT == 12608*1024

  const int M = BATCH * SEQ;  // 12608, divisible by 64
  dim3 blk(256);

  // patch embed
  conv_gemm_kernel<<<dim3((BATCH * NPAT) / 64, DMODEL / 64), blk, 0, stream>>>(
      enc, conv_w, conv_b, pos, e_buf);
  cls_kernel<<<BATCH, DMODEL, 0, stream>>>(cls, pos, e_buf);

  // ---- attention 1: q=k=v=dec_in, no mask ----
  gemm_xwt_kernel<<<dim3(M / 64, DMODEL / 64), blk, 0, stream>>>(
      dec_in, a1_wq, a1_bq, nullptr, q_buf, M, DMODEL, DMODEL, 0);
  gemm_xwt_kernel<<<dim3(M / 64, DMODEL / 64), blk, 0, stream>>>(
      dec_in, a1_wk, a1_bk, nullptr, k_buf, M, DMODEL, DMODEL, 0);
  gemm_xwt_kernel<<<dim3(M / 64, DMODEL / 64), blk, 0, stream>>>(
      dec_in, a1_wv, a1_bv, nullptr, v_buf, M, DMODEL, DMODEL, 0);
  attn_kernel<<<BATCH * NH, blk, 0, stream>>>(q_buf, k_buf, v_buf, nullptr, o_buf);
  gemm_xwt_kernel<<<dim3(M / 64, DMODEL / 64), blk, 0, stream>>>(
      o_buf, a1_wo, a1_bo, dec_in, t_buf, M, DMODEL, DMODEL, 0);
  ln_kernel<<<M / 4, blk, 0, stream>>>(t_buf, ln1_g, ln1_b, x1);

  // ---- attention 2: q=k=e, v=dec_in, with mask ----
  gemm_xwt_kernel<<<dim3(M / 64, DMODEL / 64), blk, 0, stream>>>(
      e_buf, a2_wq, a2_bq, nullptr, q_buf, M, DMODEL, DMODEL, 0);
  gemm_xwt_kernel<<<dim3(M / 64, DMODEL / 64), blk, 0, stream>>>(
      e_buf, a2_wk, a2_bk, nullptr, k_buf, M, DMODEL, DMODEL, 0);
  gemm_xwt_kernel<<<dim3(M / 64, DMODEL / 64), blk, 0, stream>>>(
      dec_in, a2_wv, a2_bv, nullptr, v_buf, M, DMODEL, DMODEL, 0);
  attn_kernel<<<BATCH * NH, blk, 0, stream>>>(q_buf, k_buf, v_buf, mask, o_buf);
  gemm_xwt_kernel<<<dim3(M / 64, DMODEL / 64), blk, 0, stream>>>(
      o_buf, a2_wo, a2_bo, x1, t_buf, M, DMODEL, DMODEL, 0);
  ln_kernel<<<M / 4, blk, 0, stream>>>(t_buf, ln2_g, ln2_b, x2);

  // ---- feed-forward ----
  gemm_xwt_kernel<<<dim3(M / 64, FFDIM / 64), blk, 0, stream>>>(
      x2, ff_w1, ff_b1, nullptr, h_buf, M, FFDIM, DMODEL, 1);
  gemm_xwt_kernel<<<dim3(M / 64, DMODEL / 64), blk, 0, stream>>>(
      h_buf, ff_w2, ff_b2, x2, t_buf, M, DMODEL, FFDIM, 0);
  ln_kernel<<<M / 4, blk, 0, stream>>>(t_buf, ln3_g, ln3_b, (float*)d_out);
}

// Round 2
// 529.368 us; speedup vs baseline: 2.7636x; 2.7636x over previous
//
#include <hip/hip_runtime.h>
#include <hip/hip_bf16.h>
#include <math.h>

#define DMODEL 256
#define NH 8
#define DKH 32
#define SEQ 197
#define BATCH 64
#define NPAT 196
#define FFDIM 1024
#define KCONV 768
#define EPSLN 1e-5f
#define MROWS (BATCH * SEQ)  // 12608 = 64*197

typedef __attribute__((ext_vector_type(8))) short short8;
typedef __attribute__((ext_vector_type(4))) float floatx4;

__device__ inline short f2b(float f) {
  unsigned u = __float_as_uint(f);
  unsigned r = (u + 0x7FFFu + ((u >> 16) & 1u)) >> 16;
  return (short)r;
}
__device__ inline float b2f(short s) {
  return __uint_as_float(((unsigned)(unsigned short)s) << 16);
}

// ---------------------------------------------------------------------------
// One-shot weight prep: fp32 -> bf16, with QKV / QK concatenation.
// ---------------------------------------------------------------------------
__global__ __launch_bounds__(256) void prep_weights(
    const float* wq1, const float* wk1, const float* wv1,
    const float* bq1, const float* bk1, const float* bv1,
    const float* wq2, const float* wk2, const float* bq2, const float* bk2,
    const float* wv2s, const float* wo1, const float* wo2,
    const float* ffw1, const float* ffw2, const float* convw,
    short* Wqkv1, float* Bqkv1, short* Wqk2, float* Bqk2,
    short* Wv2, short* Wo1, short* Wo2, short* Wff1, short* Wff2, short* Wconv)
{
  int i = blockIdx.x * 256 + threadIdx.x;
  if (i < 65536) {
    Wqkv1[i] = f2b(wq1[i]); Wqkv1[65536 + i] = f2b(wk1[i]); Wqkv1[131072 + i] = f2b(wv1[i]);
    Wqk2[i] = f2b(wq2[i]);  Wqk2[65536 + i] = f2b(wk2[i]);
    Wv2[i] = f2b(wv2s[i]);  Wo1[i] = f2b(wo1[i]);  Wo2[i] = f2b(wo2[i]);
  }
  if (i < 262144) { Wff1[i] = f2b(ffw1[i]); Wff2[i] = f2b(ffw2[i]); }
  if (i < 196608) { Wconv[i] = f2b(convw[i]); }
  if (i < 256) {
    Bqkv1[i] = bq1[i]; Bqkv1[256 + i] = bk1[i]; Bqkv1[512 + i] = bv1[i];
    Bqk2[i] = bq2[i];  Bqk2[256 + i] = bk2[i];
  }
}

// Pack mask (S,S) int32 -> per-row 4x uint64 bitmask
__global__ void mask_pack(const int* __restrict__ mask, unsigned long long* __restrict__ bits)
{
  int idx = blockIdx.x * 256 + threadIdx.x;
  if (idx >= SEQ * 4) return;
  int r = idx >> 2, w = idx & 3;
  unsigned long long bb = 0ull;
  for (int j = 0; j < 64; j++) {
    int c = w * 64 + j;
    if (c < SEQ && mask[r * SEQ + c] != 0) bb |= (1ull << j);
  }
  bits[idx] = bb;
}

// cls row (index 196, appended at END per reference) + pos
__global__ void cls_kernel(const float* __restrict__ cls, const float* __restrict__ pos,
                           float* __restrict__ e)
{
  int b = blockIdx.x, d = threadIdx.x;
  e[((size_t)b * SEQ + NPAT) * DMODEL + d] = cls[d] + pos[NPAT * DMODEL + d];
}

// ---------------------------------------------------------------------------
// bf16 MFMA GEMM: C = A @ W^T (+bias)(+res)(+relu).  W bf16 (N,K) row-major.
// A fp32 (abf16=0, converted during staging) or bf16 (abf16=1), row stride K.
// 64x64 tile, 4 waves, each wave 32x32 via 2x2 mfma_f32_16x16x32_bf16.
// Writes fp32 (outf) and/or bf16 (outb).
// ---------------------------------------------------------------------------
__global__ __launch_bounds__(256) void mfma_gemm(
    const void* __restrict__ A, int abf16,
    const short* __restrict__ W, const float* __restrict__ bias,
    const float* __restrict__ res, float* __restrict__ outf,
    short* __restrict__ outb, int M, int N, int K, int relu)
{
  __shared__ short Al[64][40];
  __shared__ short Bl[64][40];
  int m0 = blockIdx.x * 64, n0 = blockIdx.y * 64;
  int t = threadIdx.x;
  int wave = t >> 6, lane = t & 63;
  int wm = (wave & 1) * 32, wn = (wave >> 1) * 32;
  int r = t >> 2, c8 = (t & 3) * 8;
  int ml = lane & 15, quad = lane >> 4;

  const float* aF = (const float*)A + (size_t)(m0 + r) * K + c8;
  const short* aB = (const short*)A + (size_t)(m0 + r) * K + c8;
  const short* wB = W + (size_t)(n0 + r) * K + c8;

  floatx4 z = {0.f, 0.f, 0.f, 0.f};
  floatx4 acc[2][2] = {{z, z}, {z, z}};

  for (int k0 = 0; k0 < K; k0 += 32) {
    short8 av;
    if (abf16) {
      av = *(const short8*)(aB + k0);
    } else {
      float4 a0 = *(const float4*)(aF + k0);
      float4 a1 = *(const float4*)(aF + k0 + 4);
      av[0] = f2b(a0.x); av[1] = f2b(a0.y); av[2] = f2b(a0.z); av[3] = f2b(a0.w);
      av[4] = f2b(a1.x); av[5] = f2b(a1.y); av[6] = f2b(a1.z); av[7] = f2b(a1.w);
    }
    short8 wv = *(const short8*)(wB + k0);
    *(short8*)&Al[r][c8] = av;
    *(short8*)&Bl[r][c8] = wv;
    __syncthreads();
    short8 af0 = *(const short8*)&Al[wm + ml][quad * 8];
    short8 af1 = *(const short8*)&Al[wm + 16 + ml][quad * 8];
    short8 bf0 = *(const short8*)&Bl[wn + ml][quad * 8];
    short8 bf1 = *(const short8*)&Bl[wn + 16 + ml][quad * 8];
    acc[0][0] = __builtin_amdgcn_mfma_f32_16x16x32_bf16(af0, bf0, acc[0][0], 0, 0, 0);
    acc[0][1] = __builtin_amdgcn_mfma_f32_16x16x32_bf16(af0, bf1, acc[0][1], 0, 0, 0);
    acc[1][0] = __builtin_amdgcn_mfma_f32_16x16x32_bf16(af1, bf0, acc[1][0], 0, 0, 0);
    acc[1][1] = __builtin_amdgcn_mfma_f32_16x16x32_bf16(af1, bf1, acc[1][1], 0, 0, 0);
    __syncthreads();
  }
#pragma unroll
  for (int i = 0; i < 2; i++)
#pragma unroll
    for (int j = 0; j < 2; j++)
#pragma unroll
      for (int rr = 0; rr < 4; rr++) {
        int row = m0 + wm + i * 16 + quad * 4 + rr;
        int col = n0 + wn + j * 16 + ml;
        float v = acc[i][j][rr] + bias[col];
        if (res) v += res[(size_t)row * N + col];
        if (relu) v = fmaxf(v, 0.f);
        if (outf) outf[(size_t)row * N + col] = v;
        if (outb) outb[(size_t)row * N + col] = f2b(v);
      }
}

// ---------------------------------------------------------------------------
// Patch-embed conv as bf16 MFMA GEMM: M=12544, K=768, N=256, im2col on the fly.
// Epilogue adds conv_b + pos, writes fp32 into e rows (b*197 + p).
// ---------------------------------------------------------------------------
__global__ __launch_bounds__(256) void conv_mfma(
    const float* __restrict__ img, const short* __restrict__ W,
    const float* __restrict__ cb, const float* __restrict__ pos,
    float* __restrict__ e)
{
  __shared__ short Al[64][40];
  __shared__ short Bl[64][40];
  int m0 = blockIdx.x * 64, n0 = blockIdx.y * 64;
  int t = threadIdx.x;
  int wave = t >> 6, lane = t & 63;
  int wm = (wave & 1) * 32, wn = (wave >> 1) * 32;
  int r = t >> 2, c8 = (t & 3) * 8;
  int ml = lane & 15, quad = lane >> 4;

  int m = m0 + r;
  int b = m / NPAT, p = m - b * NPAT;
  int py = p / 14, px = p - py * 14;
  const float* abase = img + (size_t)b * 3 * 224 * 224 + (size_t)(py * 16) * 224 + px * 16;
  int rr_add = c8 >> 4;   // 0 or 1: second patch-row within this K-tile
  int cc = c8 & 15;       // 0 or 8
  const short* wB = W + (size_t)(n0 + r) * KCONV + c8;

  floatx4 z = {0.f, 0.f, 0.f, 0.f};
  floatx4 acc[2][2] = {{z, z}, {z, z}};

  for (int k0 = 0; k0 < KCONV; k0 += 32) {
    int ch = k0 >> 8;
    int rr = ((k0 & 255) >> 4) + rr_add;
    const float* ap = abase + (size_t)ch * (224 * 224) + rr * 224 + cc;
    float4 a0 = *(const float4*)ap;
    float4 a1 = *(const float4*)(ap + 4);
    short8 av;
    av[0] = f2b(a0.x); av[1] = f2b(a0.y); av[2] = f2b(a0.z); av[3] = f2b(a0.w);
    av[4] = f2b(a1.x); av[5] = f2b(a1.y); av[6] = f2b(a1.z); av[7] = f2b(a1.w);
    short8 wv = *(const short8*)(wB + k0);
    *(short8*)&Al[r][c8] = av;
    *(short8*)&Bl[r][c8] = wv;
    __syncthreads();
    short8 af0 = *(const short8*)&Al[wm + ml][quad * 8];
    short8 af1 = *(const short8*)&Al[wm + 16 + ml][quad * 8];
    short8 bf0 = *(const short8*)&Bl[wn + ml][quad * 8];
    short8 bf1 = *(const short8*)&Bl[wn + 16 + ml][quad * 8];
    acc[0][0] = __builtin_amdgcn_mfma_f32_16x16x32_bf16(af0, bf0, acc[0][0], 0, 0, 0);
    acc[0][1] = __builtin_amdgcn_mfma_f32_16x16x32_bf16(af0, bf1, acc[0][1], 0, 0, 0);
    acc[1][0] = __builtin_amdgcn_mfma_f32_16x16x32_bf16(af1, bf0, acc[1][0], 0, 0, 0);
    acc[1][1] = __builtin_amdgcn_mfma_f32_16x16x32_bf16(af1, bf1, acc[1][1], 0, 0, 0);
    __syncthreads();
  }
#pragma unroll
  for (int i = 0; i < 2; i++)
#pragma unroll
    for (int j = 0; j < 2; j++)
#pragma unroll
      for (int rr = 0; rr < 4; rr++) {
        int mrow = m0 + wm + i * 16 + quad * 4 + rr;
        int b2 = mrow / NPAT, p2 = mrow - b2 * NPAT;
        int col = n0 + wn + j * 16 + ml;
        e[((size_t)b2 * SEQ + p2) * DMODEL + col] =
            acc[i][j][rr] + cb[col] + pos[p2 * DMODEL + col];
      }
}

// ---------------------------------------------------------------------------
// Online-softmax attention: one block per (b,h), one thread per query row.
// K,V rows staged fp32 in LDS (read as wave-uniform broadcasts).
// q/k/v are bf16 with row strides; output bf16, stride DMODEL.
// ---------------------------------------------------------------------------
__global__ __launch_bounds__(256) void attn_online(
    const short* __restrict__ qp, int qstr,
    const short* __restrict__ kp, int kstr,
    const short* __restrict__ vp, int vstr,
    const unsigned long long* __restrict__ mbits,
    short* __restrict__ op)
{
  __shared__ float ks[SEQ][DKH];
  __shared__ float vs[SEQ][DKH];
  int bh = blockIdx.x;
  int b = bh >> 3, h = bh & 7;
  int t = threadIdx.x;
  const short* kb = kp + (size_t)b * SEQ * kstr + h * DKH;
  const short* vb = vp + (size_t)b * SEQ * vstr + h * DKH;
  for (int idx = t; idx < SEQ * 4; idx += 256) {
    int s = idx >> 2, cc = (idx & 3) * 8;
    short8 k8 = *(const short8*)(kb + (size_t)s * kstr + cc);
    short8 v8 = *(const short8*)(vb + (size_t)s * vstr + cc);
#pragma unroll
    for (int j = 0; j < 8; j++) { ks[s][cc + j] = b2f(k8[j]); vs[s][cc + j] = b2f(v8[j]); }
  }
  __syncthreads();
  if (t < SEQ) {
    const short* qb = qp + ((size_t)b * SEQ + t) * qstr + h * DKH;
    float qv[DKH];
#pragma unroll
    for (int cc = 0; cc < DKH; cc += 8) {
      short8 q8 = *(const short8*)(qb + cc);
#pragma unroll
      for (int j = 0; j < 8; j++) qv[cc + j] = b2f(q8[j]);
    }
    unsigned long long mrow[4] = {~0ull, ~0ull, ~0ull, ~0ull};
    if (mbits) {
      mrow[0] = mbits[t * 4]; mrow[1] = mbits[t * 4 + 1];
      mrow[2] = mbits[t * 4 + 2]; mrow[3] = mbits[t * 4 + 3];
    }
    const float scale = 0.17677669529663687f;  // 1/sqrt(32)
    float mx = -1e30f, l = 0.f;
    float ov[DKH];
#pragma unroll
    for (int d = 0; d < DKH; d++) ov[d] = 0.f;
    for (int kj = 0; kj < SEQ; kj++) {
      float s0 = 0.f, s1 = 0.f, s2 = 0.f, s3 = 0.f;
#pragma unroll
      for (int d = 0; d < DKH; d += 4) {
        s0 += qv[d] * ks[kj][d];
        s1 += qv[d + 1] * ks[kj][d + 1];
        s2 += qv[d + 2] * ks[kj][d + 2];
        s3 += qv[d + 3] * ks[kj][d + 3];
      }
      float s = ((s0 + s1) + (s2 + s3)) * scale;
      if (!((mrow[kj >> 6] >> (kj & 63)) & 1ull)) s = -1e38f;  // masked -> p==0
      float nm = fmaxf(mx, s);
      float alpha = __expf(mx - nm);
      float p = __expf(s - nm);
      l = l * alpha + p;
#pragma unroll
      for (int d = 0; d < DKH; d++) ov[d] = ov[d] * alpha + p * vs[kj][d];
      mx = nm;
    }
    float inv = 1.f / l;
    short* ob = op + ((size_t)b * SEQ + t) * DMODEL + h * DKH;
#pragma unroll
    for (int cc = 0; cc < DKH; cc += 8) {
      short8 o8;
#pragma unroll
      for (int j = 0; j < 8; j++) o8[j] = f2b(ov[cc + j] * inv);
      *(short8*)(ob + cc) = o8;
    }
  }
}

// ---------------------------------------------------------------------------
// LayerNorm over D=256, one 64-lane wave per row (4 rows per block).
// ---------------------------------------------------------------------------
__global__ __launch_bounds__(256) void ln_kernel(
    const float* __restrict__ x, const float* __restrict__ g,
    const float* __restrict__ bt, float* __restrict__ out)
{
  int wave = threadIdx.x >> 6, lane = threadIdx.x & 63;
  int row = blockIdx.x * 4 + wave;
  const float* xr = x + (size_t)row * DMODEL;
  float v0 = xr[lane], v1 = xr[lane + 64], v2 = xr[lane + 128], v3 = xr[lane + 192];
  float s = v0 + v1 + v2 + v3;
  for (int off = 32; off; off >>= 1) s += __shfl_down(s, off);
  s = __shfl(s, 0);
  float mean = s * (1.0f / DMODEL);
  float d0 = v0 - mean, d1 = v1 - mean, d2 = v2 - mean, d3 = v3 - mean;
  float vv = d0 * d0 + d1 * d1 + d2 * d2 + d3 * d3;
  for (int off = 32; off; off >>= 1) vv += __shfl_down(vv, off);
  vv = __shfl(vv, 0);
  float inv = rsqrtf(vv * (1.0f / DMODEL) + EPSLN);
  float* orow = out + (size_t)row * DMODEL;
  orow[lane]       = d0 * inv * g[lane]       + bt[lane];
  orow[lane + 64]  = d1 * inv * g[lane + 64]  + bt[lane + 64];
  orow[lane + 128] = d2 * inv * g[lane + 128] + bt[lane + 128];
  orow[lane + 192] = d3 * inv * g[lane + 192] + bt[lane + 192];
}

// ---------------------------------------------------------------------------
extern "C" void kernel_launch(void* const* d_in, const int* in_sizes, int n_in,
                              void* d_out, int out_size, void* d_ws, size_t ws_size,
                              hipStream_t stream)
{
  const float* enc    = (const float*)d_in[0];
  const float* dec_in = (const float*)d_in[1];
  const int*   mask   = (const int*)  d_in[2];
  const float* conv_w = (const float*)d_in[3];
  const float* conv_b = (const float*)d_in[4];
  const float* cls    = (const float*)d_in[5];
  const float* pos    = (const float*)d_in[6];
  const float* ff_w1  = (const float*)d_in[7];
  const float* ff_b1  = (const float*)d_in[8];
  const float* ff_w2  = (const float*)d_in[9];
  const float* ff_b2  = (const float*)d_in[10];
  const float* ln1_g  = (const float*)d_in[11];
  const float* ln1_b  = (const float*)d_in[12];
  const float* ln2_g  = (const float*)d_in[13];
  const float* ln2_b  = (const float*)d_in[14];
  const float* ln3_g  = (const float*)d_in[15];
  const float* ln3_b  = (const float*)d_in[16];
  const float* a1_wq = (const float*)d_in[17]; const float* a1_bq = (const float*)d_in[18];
  const float* a1_wk = (const float*)d_in[19]; const float* a1_bk = (const float*)d_in[20];
  const float* a1_wv = (const float*)d_in[21]; const float* a1_bv = (const float*)d_in[22];
  const float* a1_wo = (const float*)d_in[23]; const float* a1_bo = (const float*)d_in[24];
  const float* a2_wq = (const float*)d_in[25]; const float* a2_bq = (const float*)d_in[26];
  const float* a2_wk = (const float*)d_in[27]; const float* a2_bk = (const float*)d_in[28];
  const float* a2_wv = (const float*)d_in[29]; const float* a2_bv = (const float*)d_in[30];
  const float* a2_wo = (const float*)d_in[31]; const float* a2_bo = (const float*)d_in[32];

  // ---- workspace layout (bytes) ----
  char* wsB = (char*)d_ws;
  short* Wqkv1 = (short*)wsB;            // 196608
  short* Wqk2  = Wqkv1 + 196608;         // 131072
  short* Wv2   = Wqk2 + 131072;          // 65536
  short* Wo1   = Wv2 + 65536;            // 65536
  short* Wo2   = Wo1 + 65536;            // 65536
  short* Wff1  = Wo2 + 65536;            // 262144
  short* Wff2  = Wff1 + 262144;          // 262144
  short* Wconv = Wff2 + 262144;          // 196608
  float* Bqkv1 = (float*)(Wconv + 196608);  // 768
  float* Bqk2  = Bqkv1 + 768;               // 512
  unsigned long long* mbits = (unsigned long long*)(Bqk2 + 512);  // 788

  const size_t OFF_E  = 2621440;                            // 2.5 MB mark
  const size_t SLOTF  = (size_t)MROWS * DMODEL * 4;         // 12,910,592 B
  const size_t OFF_R2 = OFF_E + SLOTF;
  const size_t OFF_T  = OFF_R2 + 25821184;
  const size_t OFF_X1 = OFF_T + SLOTF;
  const size_t OFF_X2 = OFF_X1 + SLOTF;

  float* e_buf = (float*)(wsB + OFF_E);
  short* qkv1  = (short*)(wsB + OFF_R2);                    // [M][768] bf16
  short* o1    = (short*)(wsB + OFF_R2 + 19365888);         // [M][256] bf16
  short* qk2   = (short*)(wsB + OFF_R2);                    // [M][512] bf16 (phase B)
  short* v2    = (short*)(wsB + OFF_R2 + 12910592);         // [M][256] bf16
  short* o2    = o1;
  short* h_buf = (short*)(wsB + OFF_R2);                    // [M][1024] bf16 (phase C)
  float* t_buf = (float*)(wsB + OFF_T);
  float* x1    = (float*)(wsB + OFF_X1);
  float* x2    = (float*)(wsB + OFF_X2);

  dim3 blk(256);
  const int M = MROWS;

  prep_weights<<<1024, blk, 0, stream>>>(
      a1_wq, a1_wk, a1_wv, a1_bq, a1_bk, a1_bv,
      a2_wq, a2_wk, a2_bq, a2_bk, a2_wv, a1_wo, a2_wo,
      ff_w1, ff_w2, conv_w,
      Wqkv1, Bqkv1, Wqk2, Bqk2, Wv2, Wo1, Wo2, Wff1, Wff2, Wconv);
  mask_pack<<<4, blk, 0, stream>>>(mask, mbits);

  // patch embed
  conv_mfma<<<dim3(196, 4), blk, 0, stream>>>(enc, Wconv, conv_b, pos, e_buf);
  cls_kernel<<<BATCH, DMODEL, 0, stream>>>(cls, pos, e_buf);

  // ---- attention 1: q=k=v=dec_in, no mask ----
  mfma_gemm<<<dim3(197, 12), blk, 0, stream>>>(
      dec_in, 0, Wqkv1, Bqkv1, nullptr, nullptr, qkv1, M, 768, 256, 0);
  attn_online<<<512, blk, 0, stream>>>(
      qkv1, 768, qkv1 + 256, 768, qkv1 + 512, 768, nullptr, o1);
  mfma_gemm<<<dim3(197, 4), blk, 0, stream>>>(
      o1, 1, Wo1, a1_bo, dec_in, t_buf, nullptr, M, 256, 256, 0);
  ln_kernel<<<M / 4, blk, 0, stream>>>(t_buf, ln1_g, ln1_b, x1);

  // ---- attention 2: q=k=e, v=dec_in, mask ----
  mfma_gemm<<<dim3(197, 8), blk, 0, stream>>>(
      e_buf, 0, Wqk2, Bqk2, nullptr, nullptr, qk2, M, 512, 256, 0);
  mfma_gemm<<<dim3(197, 4), blk, 0, stream>>>(
      dec_in, 0, Wv2, a2_bv, nullptr, nullptr, v2, M, 256, 256, 0);
  attn_online<<<512, blk, 0, stream>>>(
      qk2, 512, qk2 + 256, 512, v2, 256, mbits, o2);
  mfma_gemm<<<dim3(197, 4), blk, 0, stream>>>(
      o2, 1, Wo2, a2_bo, x1, t_buf, nullptr, M, 256, 256, 0);
  ln_kernel<<<M / 4, blk, 0, stream>>>(t_buf, ln2_g, ln2_b, x2);

  // ---- feed-forward ----
  mfma_gemm<<<dim3(197, 16), blk, 0, stream>>>(
      x2, 0, Wff1, ff_b1, nullptr, nullptr, h_buf, M, FFDIM, 256, 1);
  mfma_gemm<<<dim3(197, 4), blk, 0, stream>>>(
      h_buf, 1, Wff2, ff_b2, x2, t_buf, nullptr, M, 256, 1024, 0);
  ln_kernel<<<M / 4, blk, 0, stream>>>(t_buf, ln3_g, ln3_b, (float*)d_out);
}

// Round 3
// 409.143 us; speedup vs baseline: 3.5756x; 1.2938x over previous
//
#include <hip/hip_runtime.h>
#include <hip/hip_bf16.h>
#include <math.h>

#define DMODEL 256
#define NH 8
#define DKH 32
#define SEQ 197
#define BATCH 64
#define NPAT 196
#define FFDIM 1024
#define KCONV 768
#define EPSLN 1e-5f
#define MROWS (BATCH * SEQ)  // 12608 = 64*197
#define SP 224               // SEQ padded to 7 super-tiles of 32

typedef __attribute__((ext_vector_type(8))) short short8;
typedef __attribute__((ext_vector_type(4))) short short4v;
typedef __attribute__((ext_vector_type(4))) float floatx4;

__device__ inline short f2b(float f) {
  unsigned u = __float_as_uint(f);
  unsigned r = (u + 0x7FFFu + ((u >> 16) & 1u)) >> 16;
  return (short)r;
}
__device__ inline float b2f(short s) {
  return __uint_as_float(((unsigned)(unsigned short)s) << 16);
}

// ---------------------------------------------------------------------------
// One-shot weight prep: fp32 -> bf16, with QKV / QK concatenation.
// ---------------------------------------------------------------------------
__global__ __launch_bounds__(256) void prep_weights(
    const float* wq1, const float* wk1, const float* wv1,
    const float* bq1, const float* bk1, const float* bv1,
    const float* wq2, const float* wk2, const float* bq2, const float* bk2,
    const float* wv2s, const float* wo1, const float* wo2,
    const float* ffw1, const float* ffw2, const float* convw,
    short* Wqkv1, float* Bqkv1, short* Wqk2, float* Bqk2,
    short* Wv2, short* Wo1, short* Wo2, short* Wff1, short* Wff2, short* Wconv)
{
  int i = blockIdx.x * 256 + threadIdx.x;
  if (i < 65536) {
    Wqkv1[i] = f2b(wq1[i]); Wqkv1[65536 + i] = f2b(wk1[i]); Wqkv1[131072 + i] = f2b(wv1[i]);
    Wqk2[i] = f2b(wq2[i]);  Wqk2[65536 + i] = f2b(wk2[i]);
    Wv2[i] = f2b(wv2s[i]);  Wo1[i] = f2b(wo1[i]);  Wo2[i] = f2b(wo2[i]);
  }
  if (i < 262144) { Wff1[i] = f2b(ffw1[i]); Wff2[i] = f2b(ffw2[i]); }
  if (i < 196608) { Wconv[i] = f2b(convw[i]); }
  if (i < 256) {
    Bqkv1[i] = bq1[i]; Bqkv1[256 + i] = bk1[i]; Bqkv1[512 + i] = bv1[i];
    Bqk2[i] = bq2[i];  Bqk2[256 + i] = bk2[i];
  }
}

// Pack mask (S,S) int32 -> per-row 4x uint64 bitmask; also an all-ones
// (col<SEQ) table for the unmasked attention.
__global__ void mask_pack(const int* __restrict__ mask,
                          unsigned long long* __restrict__ bits,
                          unsigned long long* __restrict__ ones)
{
  int idx = blockIdx.x * 256 + threadIdx.x;
  if (idx >= SEQ * 4) return;
  int r = idx >> 2, w = idx & 3;
  unsigned long long bb = 0ull, oo = 0ull;
  for (int j = 0; j < 64; j++) {
    int c = w * 64 + j;
    if (c < SEQ) {
      oo |= (1ull << j);
      if (mask[r * SEQ + c] != 0) bb |= (1ull << j);
    }
  }
  bits[idx] = bb;
  ones[idx] = oo;
}

// cls row (index 196, appended at END per reference) + pos
__global__ void cls_kernel(const float* __restrict__ cls, const float* __restrict__ pos,
                           float* __restrict__ e)
{
  int b = blockIdx.x, d = threadIdx.x;
  e[((size_t)b * SEQ + NPAT) * DMODEL + d] = cls[d] + pos[NPAT * DMODEL + d];
}

// ---------------------------------------------------------------------------
// bf16 MFMA GEMM: C = A @ W^T (+bias)(+res)(+relu).  W bf16 (N,K) row-major.
// ---------------------------------------------------------------------------
__global__ __launch_bounds__(256) void mfma_gemm(
    const void* __restrict__ A, int abf16,
    const short* __restrict__ W, const float* __restrict__ bias,
    const float* __restrict__ res, float* __restrict__ outf,
    short* __restrict__ outb, int M, int N, int K, int relu)
{
  __shared__ short Al[64][40];
  __shared__ short Bl[64][40];
  int m0 = blockIdx.x * 64, n0 = blockIdx.y * 64;
  int t = threadIdx.x;
  int wave = t >> 6, lane = t & 63;
  int wm = (wave & 1) * 32, wn = (wave >> 1) * 32;
  int r = t >> 2, c8 = (t & 3) * 8;
  int ml = lane & 15, quad = lane >> 4;

  const float* aF = (const float*)A + (size_t)(m0 + r) * K + c8;
  const short* aB = (const short*)A + (size_t)(m0 + r) * K + c8;
  const short* wB = W + (size_t)(n0 + r) * K + c8;

  floatx4 z = {0.f, 0.f, 0.f, 0.f};
  floatx4 acc[2][2] = {{z, z}, {z, z}};

  for (int k0 = 0; k0 < K; k0 += 32) {
    short8 av;
    if (abf16) {
      av = *(const short8*)(aB + k0);
    } else {
      float4 a0 = *(const float4*)(aF + k0);
      float4 a1 = *(const float4*)(aF + k0 + 4);
      av[0] = f2b(a0.x); av[1] = f2b(a0.y); av[2] = f2b(a0.z); av[3] = f2b(a0.w);
      av[4] = f2b(a1.x); av[5] = f2b(a1.y); av[6] = f2b(a1.z); av[7] = f2b(a1.w);
    }
    short8 wv = *(const short8*)(wB + k0);
    *(short8*)&Al[r][c8] = av;
    *(short8*)&Bl[r][c8] = wv;
    __syncthreads();
    short8 af0 = *(const short8*)&Al[wm + ml][quad * 8];
    short8 af1 = *(const short8*)&Al[wm + 16 + ml][quad * 8];
    short8 bf0 = *(const short8*)&Bl[wn + ml][quad * 8];
    short8 bf1 = *(const short8*)&Bl[wn + 16 + ml][quad * 8];
    acc[0][0] = __builtin_amdgcn_mfma_f32_16x16x32_bf16(af0, bf0, acc[0][0], 0, 0, 0);
    acc[0][1] = __builtin_amdgcn_mfma_f32_16x16x32_bf16(af0, bf1, acc[0][1], 0, 0, 0);
    acc[1][0] = __builtin_amdgcn_mfma_f32_16x16x32_bf16(af1, bf0, acc[1][0], 0, 0, 0);
    acc[1][1] = __builtin_amdgcn_mfma_f32_16x16x32_bf16(af1, bf1, acc[1][1], 0, 0, 0);
    __syncthreads();
  }
#pragma unroll
  for (int i = 0; i < 2; i++)
#pragma unroll
    for (int j = 0; j < 2; j++)
#pragma unroll
      for (int rr = 0; rr < 4; rr++) {
        int row = m0 + wm + i * 16 + quad * 4 + rr;
        int col = n0 + wn + j * 16 + ml;
        float v = acc[i][j][rr] + bias[col];
        if (res) v += res[(size_t)row * N + col];
        if (relu) v = fmaxf(v, 0.f);
        if (outf) outf[(size_t)row * N + col] = v;
        if (outb) outb[(size_t)row * N + col] = f2b(v);
      }
}

// ---------------------------------------------------------------------------
// Patch-embed conv as bf16 MFMA GEMM: M=12544, K=768, N=256, im2col on the fly.
// ---------------------------------------------------------------------------
__global__ __launch_bounds__(256) void conv_mfma(
    const float* __restrict__ img, const short* __restrict__ W,
    const float* __restrict__ cb, const float* __restrict__ pos,
    float* __restrict__ e)
{
  __shared__ short Al[64][40];
  __shared__ short Bl[64][40];
  int m0 = blockIdx.x * 64, n0 = blockIdx.y * 64;
  int t = threadIdx.x;
  int wave = t >> 6, lane = t & 63;
  int wm = (wave & 1) * 32, wn = (wave >> 1) * 32;
  int r = t >> 2, c8 = (t & 3) * 8;
  int ml = lane & 15, quad = lane >> 4;

  int m = m0 + r;
  int b = m / NPAT, p = m - b * NPAT;
  int py = p / 14, px = p - py * 14;
  const float* abase = img + (size_t)b * 3 * 224 * 224 + (size_t)(py * 16) * 224 + px * 16;
  int rr_add = c8 >> 4;
  int cc = c8 & 15;
  const short* wB = W + (size_t)(n0 + r) * KCONV + c8;

  floatx4 z = {0.f, 0.f, 0.f, 0.f};
  floatx4 acc[2][2] = {{z, z}, {z, z}};

  for (int k0 = 0; k0 < KCONV; k0 += 32) {
    int ch = k0 >> 8;
    int rr = ((k0 & 255) >> 4) + rr_add;
    const float* ap = abase + (size_t)ch * (224 * 224) + rr * 224 + cc;
    float4 a0 = *(const float4*)ap;
    float4 a1 = *(const float4*)(ap + 4);
    short8 av;
    av[0] = f2b(a0.x); av[1] = f2b(a0.y); av[2] = f2b(a0.z); av[3] = f2b(a0.w);
    av[4] = f2b(a1.x); av[5] = f2b(a1.y); av[6] = f2b(a1.z); av[7] = f2b(a1.w);
    short8 wv = *(const short8*)(wB + k0);
    *(short8*)&Al[r][c8] = av;
    *(short8*)&Bl[r][c8] = wv;
    __syncthreads();
    short8 af0 = *(const short8*)&Al[wm + ml][quad * 8];
    short8 af1 = *(const short8*)&Al[wm + 16 + ml][quad * 8];
    short8 bf0 = *(const short8*)&Bl[wn + ml][quad * 8];
    short8 bf1 = *(const short8*)&Bl[wn + 16 + ml][quad * 8];
    acc[0][0] = __builtin_amdgcn_mfma_f32_16x16x32_bf16(af0, bf0, acc[0][0], 0, 0, 0);
    acc[0][1] = __builtin_amdgcn_mfma_f32_16x16x32_bf16(af0, bf1, acc[0][1], 0, 0, 0);
    acc[1][0] = __builtin_amdgcn_mfma_f32_16x16x32_bf16(af1, bf0, acc[1][0], 0, 0, 0);
    acc[1][1] = __builtin_amdgcn_mfma_f32_16x16x32_bf16(af1, bf1, acc[1][1], 0, 0, 0);
    __syncthreads();
  }
#pragma unroll
  for (int i = 0; i < 2; i++)
#pragma unroll
    for (int j = 0; j < 2; j++)
#pragma unroll
      for (int rr = 0; rr < 4; rr++) {
        int mrow = m0 + wm + i * 16 + quad * 4 + rr;
        int b2 = mrow / NPAT, p2 = mrow - b2 * NPAT;
        int col = n0 + wn + j * 16 + ml;
        e[((size_t)b2 * SEQ + p2) * DMODEL + col] =
            acc[i][j][rr] + cb[col] + pos[p2 * DMODEL + col];
      }
}

// ---------------------------------------------------------------------------
// MFMA flash attention, S^T formulation.
// Grid (B*NH, 4); block 256 = 4 waves; each wave owns a 16-query tile.
//   S^T = K · Q^T   (A-frag = K rows from LDS; B-frag = Q rows from global)
//   C-layout: row = key-local (quad*4+r), col = query-local (lane&15)
//   -> softmax reductions: 7 in-lane ops + 2 shfl_xor; alpha lane-uniform.
//   P^T (C-layout) -> packed ds_write_b64 into ps[m][j] -> read as B-frag.
//   O^T = V^T · P^T (A-frag = V^T rows from LDS transpose).
// ---------------------------------------------------------------------------
__global__ __launch_bounds__(256) void attn_mfma(
    const short* __restrict__ qp, int qstr,
    const short* __restrict__ kp, int kstr,
    const short* __restrict__ vp, int vstr,
    const unsigned long long* __restrict__ mbits,
    short* __restrict__ op)
{
  __shared__ short ks[SP][40];        // K rows (d-major), padded stride
  __shared__ short vt[DKH][SP + 8];   // V^T [d][j], padded stride 232
  __shared__ short ps[4][16][40];     // per-wave P [m][j0..j0+31]
  int bh = blockIdx.x;
  int b = bh >> 3, h = bh & 7;
  int t = threadIdx.x;
  int wave = t >> 6, lane = t & 63;
  int ml = lane & 15, quad = lane >> 4;
  int q0 = blockIdx.y * 64 + wave * 16;

  const short* kb = kp + (size_t)b * SEQ * kstr + h * DKH;
  const short* vb = vp + (size_t)b * SEQ * vstr + h * DKH;
  // stage K rows
  for (int idx = t; idx < SEQ * 4; idx += 256) {
    int s = idx >> 2, c = (idx & 3) * 8;
    *(short8*)&ks[s][c] = *(const short8*)(kb + (size_t)s * kstr + c);
  }
  // stage V^T (transpose via scalar LDS writes)
  for (int idx = t; idx < SEQ * 4; idx += 256) {
    int s = idx >> 2, c = (idx & 3) * 8;
    short8 v8 = *(const short8*)(vb + (size_t)s * vstr + c);
#pragma unroll
    for (int j = 0; j < 8; j++) vt[c + j][s] = v8[j];
  }
  // zero V^T pad columns (j = 197..223): garbage here would poison 0*x in PV
  for (int idx = t; idx < DKH * (SP - SEQ); idx += 256) {
    int d = idx / (SP - SEQ), j = SEQ + idx - d * (SP - SEQ);
    vt[d][j] = 0;
  }
  __syncthreads();
  if (q0 >= SEQ) return;  // no barriers after this point

  int qrow = q0 + ml;
  int qc = qrow < SEQ ? qrow : SEQ - 1;
  short8 qf = *(const short8*)(qp + ((size_t)b * SEQ + qc) * qstr + h * DKH + quad * 8);
  const unsigned long long* mrow = mbits + (size_t)qc * 4;

  const float scale = 0.17677669529663687f;  // 1/sqrt(32)
  floatx4 z = {0.f, 0.f, 0.f, 0.f};
  floatx4 accO0 = z, accO1 = z;
  float mrun = -1e30f, lrun = 0.f;

  for (int st = 0; st < 7; st++) {
    int j0 = st * 32;
    short8 k0 = *(const short8*)&ks[j0 + ml][quad * 8];
    short8 k1 = *(const short8*)&ks[j0 + 16 + ml][quad * 8];
    floatx4 s0 = __builtin_amdgcn_mfma_f32_16x16x32_bf16(k0, qf, z, 0, 0, 0);
    floatx4 s1 = __builtin_amdgcn_mfma_f32_16x16x32_bf16(k1, qf, z, 0, 0, 0);
    unsigned long long mb = mrow[j0 >> 6] >> (j0 & 63);  // low 32 bits valid
    float sv[8];
#pragma unroll
    for (int r = 0; r < 4; r++) {
      int jl = quad * 4 + r;
      sv[r]     = ((mb >> jl) & 1ull)        ? s0[r] * scale : -1e38f;
      sv[4 + r] = ((mb >> (16 + jl)) & 1ull) ? s1[r] * scale : -1e38f;
    }
    float tm = sv[0];
#pragma unroll
    for (int i = 1; i < 8; i++) tm = fmaxf(tm, sv[i]);
    tm = fmaxf(tm, __shfl_xor(tm, 16));
    tm = fmaxf(tm, __shfl_xor(tm, 32));
    float nm = fmaxf(mrun, tm);
    float alpha = __expf(mrun - nm);
    float pv[8];
    float psum = 0.f;
#pragma unroll
    for (int i = 0; i < 8; i++) { pv[i] = __expf(sv[i] - nm); psum += pv[i]; }
    psum += __shfl_xor(psum, 16);
    psum += __shfl_xor(psum, 32);
    lrun = lrun * alpha + psum;
    mrun = nm;
    accO0 = accO0 * alpha;
    accO1 = accO1 * alpha;
    short4v p0, p1;
#pragma unroll
    for (int r = 0; r < 4; r++) { p0[r] = f2b(pv[r]); p1[r] = f2b(pv[4 + r]); }
    *(short4v*)&ps[wave][ml][quad * 4]      = p0;
    *(short4v*)&ps[wave][ml][16 + quad * 4] = p1;
    __asm__ volatile("s_waitcnt lgkmcnt(0)" ::: "memory");  // wave-local RAW
    short8 pf = *(const short8*)&ps[wave][ml][quad * 8];
    short8 vf0 = *(const short8*)&vt[ml][j0 + quad * 8];
    short8 vf1 = *(const short8*)&vt[16 + ml][j0 + quad * 8];
    accO0 = __builtin_amdgcn_mfma_f32_16x16x32_bf16(vf0, pf, accO0, 0, 0, 0);
    accO1 = __builtin_amdgcn_mfma_f32_16x16x32_bf16(vf1, pf, accO1, 0, 0, 0);
  }
  if (qrow < SEQ) {
    float inv = 1.f / lrun;
    short* ob = op + ((size_t)b * SEQ + qrow) * DMODEL + h * DKH;
    short4v o0, o1;
#pragma unroll
    for (int r = 0; r < 4; r++) {
      o0[r] = f2b(accO0[r] * inv);
      o1[r] = f2b(accO1[r] * inv);
    }
    *(short4v*)(ob + quad * 4)      = o0;
    *(short4v*)(ob + 16 + quad * 4) = o1;
  }
}

// ---------------------------------------------------------------------------
// LayerNorm over D=256, one 64-lane wave per row (4 rows per block).
// ---------------------------------------------------------------------------
__global__ __launch_bounds__(256) void ln_kernel(
    const float* __restrict__ x, const float* __restrict__ g,
    const float* __restrict__ bt, float* __restrict__ out)
{
  int wave = threadIdx.x >> 6, lane = threadIdx.x & 63;
  int row = blockIdx.x * 4 + wave;
  const float* xr = x + (size_t)row * DMODEL;
  float v0 = xr[lane], v1 = xr[lane + 64], v2 = xr[lane + 128], v3 = xr[lane + 192];
  float s = v0 + v1 + v2 + v3;
  for (int off = 32; off; off >>= 1) s += __shfl_down(s, off);
  s = __shfl(s, 0);
  float mean = s * (1.0f / DMODEL);
  float d0 = v0 - mean, d1 = v1 - mean, d2 = v2 - mean, d3 = v3 - mean;
  float vv = d0 * d0 + d1 * d1 + d2 * d2 + d3 * d3;
  for (int off = 32; off; off >>= 1) vv += __shfl_down(vv, off);
  vv = __shfl(vv, 0);
  float inv = rsqrtf(vv * (1.0f / DMODEL) + EPSLN);
  float* orow = out + (size_t)row * DMODEL;
  orow[lane]       = d0 * inv * g[lane]       + bt[lane];
  orow[lane + 64]  = d1 * inv * g[lane + 64]  + bt[lane + 64];
  orow[lane + 128] = d2 * inv * g[lane + 128] + bt[lane + 128];
  orow[lane + 192] = d3 * inv * g[lane + 192] + bt[lane + 192];
}

// ---------------------------------------------------------------------------
extern "C" void kernel_launch(void* const* d_in, const int* in_sizes, int n_in,
                              void* d_out, int out_size, void* d_ws, size_t ws_size,
                              hipStream_t stream)
{
  const float* enc    = (const float*)d_in[0];
  const float* dec_in = (const float*)d_in[1];
  const int*   mask   = (const int*)  d_in[2];
  const float* conv_w = (const float*)d_in[3];
  const float* conv_b = (const float*)d_in[4];
  const float* cls    = (const float*)d_in[5];
  const float* pos    = (const float*)d_in[6];
  const float* ff_w1  = (const float*)d_in[7];
  const float* ff_b1  = (const float*)d_in[8];
  const float* ff_w2  = (const float*)d_in[9];
  const float* ff_b2  = (const float*)d_in[10];
  const float* ln1_g  = (const float*)d_in[11];
  const float* ln1_b  = (const float*)d_in[12];
  const float* ln2_g  = (const float*)d_in[13];
  const float* ln2_b  = (const float*)d_in[14];
  const float* ln3_g  = (const float*)d_in[15];
  const float* ln3_b  = (const float*)d_in[16];
  const float* a1_wq = (const float*)d_in[17]; const float* a1_bq = (const float*)d_in[18];
  const float* a1_wk = (const float*)d_in[19]; const float* a1_bk = (const float*)d_in[20];
  const float* a1_wv = (const float*)d_in[21]; const float* a1_bv = (const float*)d_in[22];
  const float* a1_wo = (const float*)d_in[23]; const float* a1_bo = (const float*)d_in[24];
  const float* a2_wq = (const float*)d_in[25]; const float* a2_bq = (const float*)d_in[26];
  const float* a2_wk = (const float*)d_in[27]; const float* a2_bk = (const float*)d_in[28];
  const float* a2_wv = (const float*)d_in[29]; const float* a2_bv = (const float*)d_in[30];
  const float* a2_wo = (const float*)d_in[31]; const float* a2_bo = (const float*)d_in[32];

  // ---- workspace layout ----
  char* wsB = (char*)d_ws;
  short* Wqkv1 = (short*)wsB;            // 196608 shorts
  short* Wqk2  = Wqkv1 + 196608;         // 131072
  short* Wv2   = Wqk2 + 131072;          // 65536
  short* Wo1   = Wv2 + 65536;            // 65536
  short* Wo2   = Wo1 + 65536;            // 65536
  short* Wff1  = Wo2 + 65536;            // 262144
  short* Wff2  = Wff1 + 262144;          // 262144
  short* Wconv = Wff2 + 262144;          // 196608
  float* Bqkv1 = (float*)(Wconv + 196608);  // 768 floats
  float* Bqk2  = Bqkv1 + 768;               // 512 floats
  unsigned long long* mbits = (unsigned long long*)(Bqk2 + 512);  // 788 u64
  unsigned long long* mones = mbits + 788;                        // 788 u64

  const size_t OFF_E  = 2621440;
  const size_t SLOTF  = (size_t)MROWS * DMODEL * 4;
  const size_t OFF_R2 = OFF_E + SLOTF;
  const size_t OFF_T  = OFF_R2 + 25821184;
  const size_t OFF_X1 = OFF_T + SLOTF;
  const size_t OFF_X2 = OFF_X1 + SLOTF;

  float* e_buf = (float*)(wsB + OFF_E);
  short* qkv1  = (short*)(wsB + OFF_R2);
  short* o1    = (short*)(wsB + OFF_R2 + 19365888);
  short* qk2   = (short*)(wsB + OFF_R2);
  short* v2    = (short*)(wsB + OFF_R2 + 12910592);
  short* o2    = o1;
  short* h_buf = (short*)(wsB + OFF_R2);
  float* t_buf = (float*)(wsB + OFF_T);
  float* x1    = (float*)(wsB + OFF_X1);
  float* x2    = (float*)(wsB + OFF_X2);

  dim3 blk(256);
  const int M = MROWS;

  prep_weights<<<1024, blk, 0, stream>>>(
      a1_wq, a1_wk, a1_wv, a1_bq, a1_bk, a1_bv,
      a2_wq, a2_wk, a2_bq, a2_bk, a2_wv, a1_wo, a2_wo,
      ff_w1, ff_w2, conv_w,
      Wqkv1, Bqkv1, Wqk2, Bqk2, Wv2, Wo1, Wo2, Wff1, Wff2, Wconv);
  mask_pack<<<4, blk, 0, stream>>>(mask, mbits, mones);

  // patch embed
  conv_mfma<<<dim3(196, 4), blk, 0, stream>>>(enc, Wconv, conv_b, pos, e_buf);
  cls_kernel<<<BATCH, DMODEL, 0, stream>>>(cls, pos, e_buf);

  // ---- attention 1: q=k=v=dec_in, no mask ----
  mfma_gemm<<<dim3(197, 12), blk, 0, stream>>>(
      dec_in, 0, Wqkv1, Bqkv1, nullptr, nullptr, qkv1, M, 768, 256, 0);
  attn_mfma<<<dim3(512, 4), blk, 0, stream>>>(
      qkv1, 768, qkv1 + 256, 768, qkv1 + 512, 768, mones, o1);
  mfma_gemm<<<dim3(197, 4), blk, 0, stream>>>(
      o1, 1, Wo1, a1_bo, dec_in, t_buf, nullptr, M, 256, 256, 0);
  ln_kernel<<<M / 4, blk, 0, stream>>>(t_buf, ln1_g, ln1_b, x1);

  // ---- attention 2: q=k=e, v=dec_in, mask ----
  mfma_gemm<<<dim3(197, 8), blk, 0, stream>>>(
      e_buf, 0, Wqk2, Bqk2, nullptr, nullptr, qk2, M, 512, 256, 0);
  mfma_gemm<<<dim3(197, 4), blk, 0, stream>>>(
      dec_in, 0, Wv2, a2_bv, nullptr, nullptr, v2, M, 256, 256, 0);
  attn_mfma<<<dim3(512, 4), blk, 0, stream>>>(
      qk2, 512, qk2 + 256, 512, v2, 256, mbits, o2);
  mfma_gemm<<<dim3(197, 4), blk, 0, stream>>>(
      o2, 1, Wo2, a2_bo, x1, t_buf, nullptr, M, 256, 256, 0);
  ln_kernel<<<M / 4, blk, 0, stream>>>(t_buf, ln2_g, ln2_b, x2);

  // ---- feed-forward ----
  mfma_gemm<<<dim3(197, 16), blk, 0, stream>>>(
      x2, 0, Wff1, ff_b1, nullptr, nullptr, h_buf, M, FFDIM, 256, 1);
  mfma_gemm<<<dim3(197, 4), blk, 0, stream>>>(
      h_buf, 1, Wff2, ff_b2, x2, t_buf, nullptr, M, 256, 1024, 0);
  ln_kernel<<<M / 4, blk, 0, stream>>>(t_buf, ln3_g, ln3_b, (float*)d_out);
}